// Round 1
// 145.694 us; speedup vs baseline: 1.0218x; 1.0218x over previous
//
#include <hip/hip_runtime.h>

#define BB 32
#define NN 2048
#define DD 65
#define HH 64
#define ST 68                // padded leading dim (16B-aligned float4 frags)
#define TILE (DD * ST)       // 4420 floats per padded 65x65 matrix
#define CC 32                // x chunks per batch (64 rows each)

__device__ __forceinline__ float4 f4add(float4 a, float4 b) {
  return make_float4(a.x + b.x, a.y + b.y, a.z + b.z, a.w + b.w);
}

// ---------------------------------------------------------------------------
// k1: partial Gram P[b][c] = (64-row x chunk)^T (chunk), 65x65 stride-68.
// C=32 -> 1024 blocks (4/CU: TLP hides LDS latency), single round.
// 16x16 threads, 4x4 regs over the 64x64 core; ty==0 patches row/col 64.
// ---------------------------------------------------------------------------
__global__ __launch_bounds__(256) void k1_gram(const float* __restrict__ x,
                                               float* __restrict__ P) {
  __shared__ __align__(16) float Xl[64 * ST];
  const int t = (int)threadIdx.x;
  const int tx = t & 15, ty = t >> 4;
  const int blk = (int)blockIdx.x;
  const int b = blk >> 5, c = blk & 31;
  const float* src = x + ((size_t)b * NN + (size_t)c * 64) * DD;

  {  // batched staging: 17 independent loads in flight
    float tmp[17];
#pragma unroll
    for (int q = 0; q < 17; q++) {
      const int idx = t + 256 * q;
      if (idx < 64 * DD) tmp[q] = src[idx];
    }
#pragma unroll
    for (int q = 0; q < 17; q++) {
      const int idx = t + 256 * q;
      if (idx < 64 * DD) {
        const int r = idx / DD;
        Xl[r * ST + (idx - r * DD)] = tmp[q];
      }
    }
  }
  __syncthreads();

  float g[4][4] = {};
  float g64[4] = {};
  float gcc = 0.f;
  for (int n = 0; n < 64; n++) {
    float rowf[4], colf[4];
    *(float4*)rowf = *(const float4*)&Xl[n * ST + 4 * ty];
    *(float4*)colf = *(const float4*)&Xl[n * ST + 4 * tx];
#pragma unroll
    for (int r = 0; r < 4; r++)
#pragma unroll
      for (int cc = 0; cc < 4; cc++)
        g[r][cc] = fmaf(rowf[r], colf[cc], g[r][cc]);
    if (ty == 0) {
      float x64 = Xl[n * ST + 64];
#pragma unroll
      for (int cc = 0; cc < 4; cc++) g64[cc] = fmaf(x64, colf[cc], g64[cc]);
      if (tx == 0) gcc = fmaf(x64, x64, gcc);
    }
  }
  float* Pp = P + (size_t)blk * TILE;
#pragma unroll
  for (int r = 0; r < 4; r++)
    *(float4*)&Pp[(4 * ty + r) * ST + 4 * tx] = *(float4*)g[r];
  if (ty == 0) {
    *(float4*)&Pp[64 * ST + 4 * tx] = *(float4*)g64;  // G[64][j]
#pragma unroll
    for (int cc = 0; cc < 4; cc++)
      Pp[(4 * tx + cc) * ST + 64] = g64[cc];          // G[i][64] by symmetry
    if (tx == 0) Pp[64 * ST + 64] = gcc;
  }
}

// ---------------------------------------------------------------------------
// kred: G[b] = sum over 32 chunk tiles of P[b]. 160 blocks (5 per batch),
// one float4 slot per thread, 8 loads in flight + tree sum (x4 groups).
// ---------------------------------------------------------------------------
__global__ __launch_bounds__(256) void kred(const float* __restrict__ P,
                                            float* __restrict__ G) {
  const int t = (int)threadIdx.x;
  const int blk = (int)blockIdx.x;
  const int b = blk / 5, s = blk - b * 5;
  const int Q = TILE / 4;  // 1105
  const int i4 = s * 256 + t;
  if (i4 < Q) {
    const float4* Pb = (const float4*)(P + (size_t)b * CC * TILE);
    float4 acc = make_float4(0.f, 0.f, 0.f, 0.f);
#pragma unroll
    for (int grp = 0; grp < 4; grp++) {
      float4 v[8];
#pragma unroll
      for (int cc = 0; cc < 8; cc++)
        v[cc] = Pb[(size_t)(8 * grp + cc) * Q + i4];
#pragma unroll
      for (int stp = 4; stp >= 1; stp >>= 1)
#pragma unroll
        for (int cc = 0; cc < stp; cc++) v[cc] = f4add(v[cc], v[cc + stp]);
      acc = f4add(acc, v[0]);
    }
    ((float4*)(G + (size_t)b * TILE))[i4] = acc;
  }
}

// ---------------------------------------------------------------------------
// k2b: ROW-PARALLEL chain. T[i,:] = M[i,:] G Wv^T with M = Wq^T Wk.
// Grid = 32 batches x 9 row-groups (8 rows each, last group 1 row) = 288
// blocks -> whole chip active instead of 32 CUs; each phase is an 8-row
// strip so the latency-exposed serial chain of the old k2 disappears.
// Threads: 32x8 (tx 0..31, ty 0..7); each thread owns cols {tx, tx+32} and
// (tx==0) col 64 of its row; col-64 FMA is computed uniformly (broadcast
// read) and only stored by tx==0 to avoid divergence.
// ---------------------------------------------------------------------------
__global__ __launch_bounds__(256) void k2_chain(
    const float* __restrict__ Wq, const float* __restrict__ Wk,
    const float* __restrict__ Wv, const float* __restrict__ G,
    float* __restrict__ Tm) {
  __shared__ __align__(16) float WqL[HH * ST];   // Wq[h][d]
  __shared__ __align__(16) float WkL[HH * ST];   // Wk[h][d]
  __shared__ __align__(16) float GL[TILE];       // G[k][j]
  __shared__ __align__(16) float WvT[TILE];      // WvT[k][j] = Wv[j][k]
  __shared__ __align__(16) float Mr[8 * ST];     // 8 M rows
  __shared__ __align__(16) float Rr[8 * ST];     // 8 R rows

  const int t = (int)threadIdx.x;
  const int tx = t & 31, ty = t >> 5;
  const int blk = (int)blockIdx.x;
  const int b = blk / 9, rg = blk - b * 9;
  const int i = 8 * rg + ty;          // this thread's T row
  const bool alive = (i < DD);
  const int ic = alive ? i : 0;       // safe LDS addressing for dead rows

  // ---- stage Wq, Wk (batched, 34 loads in flight) ----
  {
    float tq[17], tk[17];
#pragma unroll
    for (int q = 0; q < 17; q++) {
      const int idx = t + 256 * q;
      if (idx < HH * DD) { tq[q] = Wq[idx]; tk[q] = Wk[idx]; }
    }
#pragma unroll
    for (int q = 0; q < 17; q++) {
      const int idx = t + 256 * q;
      if (idx < HH * DD) {
        const int r = idx / DD, cc = idx - r * DD;
        WqL[r * ST + cc] = tq[q];
        WkL[r * ST + cc] = tk[q];
      }
    }
  }
  // ---- stage G (pure float4 copy) ----
  {
    const float4* Gb4 = (const float4*)(G + (size_t)b * TILE);
    float4 tG[5];
#pragma unroll
    for (int q = 0; q < 5; q++) {
      const int i4 = t + 256 * q;
      if (i4 < TILE / 4) tG[q] = Gb4[i4];
    }
#pragma unroll
    for (int q = 0; q < 5; q++) {
      const int i4 = t + 256 * q;
      if (i4 < TILE / 4) *((float4*)GL + i4) = tG[q];
    }
  }
  // ---- stage Wv transposed ----
  {
    float tv[17];
#pragma unroll
    for (int q = 0; q < 17; q++) {
      const int idx = t + 256 * q;
      if (idx < DD * DD) tv[q] = Wv[idx];
    }
#pragma unroll
    for (int q = 0; q < 17; q++) {
      const int idx = t + 256 * q;
      if (idx < DD * DD) {
        const int j = idx / DD, k = idx - j * DD;
        WvT[k * ST + j] = tv[q];
      }
    }
  }
  __syncthreads();

  // ---- phase M: M[i][j] = sum_h Wq[h][i] Wk[h][j], j in {tx, tx+32, 64} ----
  {
    float m0 = 0.f, m1 = 0.f, m2 = 0.f;
    for (int h = 0; h < HH; h++) {
      const float wq = WqL[h * ST + ic];
      m0 = fmaf(wq, WkL[h * ST + tx], m0);
      m1 = fmaf(wq, WkL[h * ST + tx + 32], m1);
      m2 = fmaf(wq, WkL[h * ST + 64], m2);
    }
    if (alive) {
      Mr[ty * ST + tx] = m0;
      Mr[ty * ST + tx + 32] = m1;
      if (tx == 0) Mr[ty * ST + 64] = m2;
    }
  }
  __syncthreads();

  // ---- phase R: R[i][j] = sum_k M[i][k] G[k][j] ----
  {
    float r0 = 0.f, r1 = 0.f, r2 = 0.f;
    for (int k = 0; k < DD; k++) {
      const float mm = Mr[ty * ST + k];
      r0 = fmaf(mm, GL[k * ST + tx], r0);
      r1 = fmaf(mm, GL[k * ST + tx + 32], r1);
      r2 = fmaf(mm, GL[k * ST + 64], r2);
    }
    if (alive) {
      Rr[ty * ST + tx] = r0;
      Rr[ty * ST + tx + 32] = r1;
      if (tx == 0) Rr[ty * ST + 64] = r2;
    }
  }
  __syncthreads();

  // ---- phase T: T[i][j] = sum_k R[i][k] Wv[j][k] -> global ----
  {
    float t0 = 0.f, t1 = 0.f, t2 = 0.f;
    for (int k = 0; k < DD; k++) {
      const float rv = Rr[ty * ST + k];
      t0 = fmaf(rv, WvT[k * ST + tx], t0);
      t1 = fmaf(rv, WvT[k * ST + tx + 32], t1);
      t2 = fmaf(rv, WvT[k * ST + 64], t2);
    }
    if (alive) {
      float* Tb = Tm + (size_t)b * TILE + (size_t)i * ST;
      Tb[tx] = t0;
      Tb[tx + 32] = t1;
      if (tx == 0) Tb[64] = t2;
    }
  }
}

// ---------------------------------------------------------------------------
// k3: out[b] = x[b] @ T[b]. 64 rows per block; T staged as pure float4 copy,
// x staged batched; 4x4 reg tiling. Inner loop k-tiled by 4 so the A-operand
// (xa) loads become ds_read_b128 instead of 4x ds_read_b32 (ST=68, kk%4==0
// keeps 16B alignment); k=64 handled in a scalar tail. tx==0 patches col 64.
// ---------------------------------------------------------------------------
__global__ __launch_bounds__(256) void k3_out(const float* __restrict__ x,
                                              const float* __restrict__ Tt,
                                              float* __restrict__ out) {
  __shared__ __align__(16) float Tl[TILE];
  __shared__ __align__(16) float Xl[64 * ST];
  const int t = (int)threadIdx.x;
  const int tx = t & 15, ty = t >> 4;
  const int blk = (int)blockIdx.x;
  const int b = blk >> 5;           // 32 blocks per batch
  const int rb = (blk & 31) * 64;
  const float4* Tg4 = (const float4*)(Tt + (size_t)b * TILE);
  const float* src = x + ((size_t)b * NN + rb) * DD;
  {
    float4 tT[5];
    float tX[17];
#pragma unroll
    for (int q = 0; q < 5; q++) {
      const int i4 = t + 256 * q;
      if (i4 < TILE / 4) tT[q] = Tg4[i4];
    }
#pragma unroll
    for (int q = 0; q < 17; q++) {
      const int idx = t + 256 * q;
      if (idx < 64 * DD) tX[q] = src[idx];
    }
#pragma unroll
    for (int q = 0; q < 5; q++) {
      const int i4 = t + 256 * q;
      if (i4 < TILE / 4) *((float4*)Tl + i4) = tT[q];
    }
#pragma unroll
    for (int q = 0; q < 17; q++) {
      const int idx = t + 256 * q;
      if (idx < 64 * DD) {
        const int r = idx / DD;
        Xl[r * ST + (idx - r * DD)] = tX[q];
      }
    }
  }
  __syncthreads();

  float o[4][4] = {}, o64[4] = {};
  for (int kk = 0; kk < 64; kk += 4) {
    float xa4[4][4];  // [r][e]: 4 k-values per row, one b128 each
#pragma unroll
    for (int r = 0; r < 4; r++)
      *(float4*)xa4[r] = *(const float4*)&Xl[(4 * ty + r) * ST + kk];
#pragma unroll
    for (int e = 0; e < 4; e++) {
      const int k = kk + e;
      float tb[4];
      *(float4*)tb = *(const float4*)&Tl[k * ST + 4 * tx];
#pragma unroll
      for (int r = 0; r < 4; r++)
#pragma unroll
        for (int cc = 0; cc < 4; cc++)
          o[r][cc] = fmaf(xa4[r][e], tb[cc], o[r][cc]);
      if (tx == 0) {
        float t64 = Tl[k * ST + 64];
#pragma unroll
        for (int r = 0; r < 4; r++) o64[r] = fmaf(xa4[r][e], t64, o64[r]);
      }
    }
  }
  {  // k = 64 tail
    float xs[4];
#pragma unroll
    for (int r = 0; r < 4; r++) xs[r] = Xl[(4 * ty + r) * ST + 64];
    float tb[4];
    *(float4*)tb = *(const float4*)&Tl[64 * ST + 4 * tx];
#pragma unroll
    for (int r = 0; r < 4; r++)
#pragma unroll
      for (int cc = 0; cc < 4; cc++)
        o[r][cc] = fmaf(xs[r], tb[cc], o[r][cc]);
    if (tx == 0) {
      float t64 = Tl[64 * ST + 64];
#pragma unroll
      for (int r = 0; r < 4; r++) o64[r] = fmaf(xs[r], t64, o64[r]);
    }
  }

  float* ob = out + ((size_t)b * NN + rb) * DD;
#pragma unroll
  for (int r = 0; r < 4; r++)
#pragma unroll
    for (int cc = 0; cc < 4; cc++)
      ob[(4 * ty + r) * DD + 4 * tx + cc] = o[r][cc];
  if (tx == 0) {
#pragma unroll
    for (int r = 0; r < 4; r++) ob[(4 * ty + r) * DD + 64] = o64[r];
  }
}

extern "C" void kernel_launch(void* const* d_in, const int* in_sizes, int n_in,
                              void* d_out, int out_size, void* d_ws,
                              size_t ws_size, hipStream_t stream) {
  const float* x = (const float*)d_in[0];
  const float* Wq = (const float*)d_in[1];
  const float* Wk = (const float*)d_in[2];
  const float* Wv = (const float*)d_in[3];
  float* out = (float*)d_out;

  // Workspace: P[B*32 tiles] (18.1 MB) + G[B tiles] + T[B tiles] (~0.6 MB ea).
  float* P = (float*)d_ws;
  float* G = P + (size_t)BB * CC * TILE;
  float* Tm = G + (size_t)BB * TILE;

  k1_gram<<<BB * CC, 256, 0, stream>>>(x, P);
  kred<<<BB * 5, 256, 0, stream>>>(P, G);
  k2_chain<<<BB * 9, 256, 0, stream>>>(Wq, Wk, Wv, G, Tm);
  k3_out<<<BB * CC, 256, 0, stream>>>(x, Tm, out);
  (void)in_sizes; (void)n_in; (void)out_size; (void)ws_size;
}

// Round 2
// 117.102 us; speedup vs baseline: 1.2713x; 1.2442x over previous
//
#include <hip/hip_runtime.h>

#define BB 32
#define NN 2048
#define DD 65
#define HH 64
#define ST 68                // padded leading dim (16B-aligned float4 frags)
#define TILE (DD * ST)       // 4420 floats per padded 65x65 matrix
#define CC 32                // x chunks per batch (64 rows each)

__device__ __forceinline__ float4 f4add(float4 a, float4 b) {
  return make_float4(a.x + b.x, a.y + b.y, a.z + b.z, a.w + b.w);
}

// async global->LDS, 16B per lane, wave-uniform LDS base + lane*16
#define GL2LDS(g, l)                                             \
  __builtin_amdgcn_global_load_lds(                              \
      (const __attribute__((address_space(1))) void*)(g),        \
      (__attribute__((address_space(3))) void*)(l), 16, 0, 0)

// ---------------------------------------------------------------------------
// k1: partial Gram P[b][c] = (64-row x chunk)^T (chunk), 65x65 stride-68.
// 1024 blocks. __launch_bounds__(256,6) caps VGPR ~85 -> 6 blocks/CU
// (24 waves/CU) so ds_read/global latency is TLP-hidden. Staging uses 3
// passes of 6 temps (peak regs down from 17). Edge (row/col 64) FMAs are
// computed by ALL lanes (no divergent branches in the loop); stores are
// predicated.
// ---------------------------------------------------------------------------
__global__ __launch_bounds__(256, 6) void k1_gram(const float* __restrict__ x,
                                                  float* __restrict__ P) {
  __shared__ __align__(16) float Xl[64 * ST];
  const int t = (int)threadIdx.x;
  const int tx = t & 15, ty = t >> 4;
  const int blk = (int)blockIdx.x;
  const int b = blk >> 5, c = blk & 31;
  const float* src = x + ((size_t)b * NN + (size_t)c * 64) * DD;

  {  // staging: 3 passes x 6 temps (17 total slots of 256)
#pragma unroll
    for (int p = 0; p < 3; p++) {
      float tmp[6];
      const int cnt = (p == 2) ? 5 : 6;
#pragma unroll
      for (int q = 0; q < 6; q++) {
        const int idx = t + 256 * (6 * p + q);
        if (q < cnt && idx < 64 * DD) tmp[q] = src[idx];
      }
#pragma unroll
      for (int q = 0; q < 6; q++) {
        const int idx = t + 256 * (6 * p + q);
        if (q < cnt && idx < 64 * DD) {
          const int r = idx / DD;
          Xl[r * ST + (idx - r * DD)] = tmp[q];
        }
      }
    }
  }
  __syncthreads();

  float g[4][4] = {};
  float g64[4] = {};
  float gcc = 0.f;
  for (int n = 0; n < 64; n++) {
    float rowf[4], colf[4];
    *(float4*)rowf = *(const float4*)&Xl[n * ST + 4 * ty];
    *(float4*)colf = *(const float4*)&Xl[n * ST + 4 * tx];
    const float x64 = Xl[n * ST + 64];  // broadcast, conflict-free
#pragma unroll
    for (int r = 0; r < 4; r++)
#pragma unroll
      for (int cc = 0; cc < 4; cc++)
        g[r][cc] = fmaf(rowf[r], colf[cc], g[r][cc]);
#pragma unroll
    for (int cc = 0; cc < 4; cc++) g64[cc] = fmaf(x64, colf[cc], g64[cc]);
    gcc = fmaf(x64, x64, gcc);
  }
  float* Pp = P + (size_t)blk * TILE;
#pragma unroll
  for (int r = 0; r < 4; r++)
    *(float4*)&Pp[(4 * ty + r) * ST + 4 * tx] = *(float4*)g[r];
  if (ty == 0) {
    *(float4*)&Pp[64 * ST + 4 * tx] = *(float4*)g64;  // G[64][j]
#pragma unroll
    for (int cc = 0; cc < 4; cc++)
      Pp[(4 * tx + cc) * ST + 64] = g64[cc];          // G[i][64] by symmetry
    if (tx == 0) Pp[64 * ST + 64] = gcc;
  }
}

// ---------------------------------------------------------------------------
// kred: G[b] = sum over 32 chunk tiles of P[b]. 160 blocks (5 per batch),
// one float4 slot per thread, 8 loads in flight + tree sum (x4 groups).
// ---------------------------------------------------------------------------
__global__ __launch_bounds__(256) void kred(const float* __restrict__ P,
                                            float* __restrict__ G) {
  const int t = (int)threadIdx.x;
  const int blk = (int)blockIdx.x;
  const int b = blk / 5, s = blk - b * 5;
  const int Q = TILE / 4;  // 1105
  const int i4 = s * 256 + t;
  if (i4 < Q) {
    const float4* Pb = (const float4*)(P + (size_t)b * CC * TILE);
    float4 acc = make_float4(0.f, 0.f, 0.f, 0.f);
#pragma unroll
    for (int grp = 0; grp < 4; grp++) {
      float4 v[8];
#pragma unroll
      for (int cc = 0; cc < 8; cc++)
        v[cc] = Pb[(size_t)(8 * grp + cc) * Q + i4];
#pragma unroll
      for (int stp = 4; stp >= 1; stp >>= 1)
#pragma unroll
        for (int cc = 0; cc < stp; cc++) v[cc] = f4add(v[cc], v[cc + stp]);
      acc = f4add(acc, v[0]);
    }
    ((float4*)(G + (size_t)b * TILE))[i4] = acc;
  }
}

// ---------------------------------------------------------------------------
// k2b: ROW-PARALLEL chain. T[i,:] = M[i,:] G Wv^T with M = Wq^T Wk.
// 288 blocks (9 row-groups x 32 batches); unchanged from round 1.
// ---------------------------------------------------------------------------
__global__ __launch_bounds__(256) void k2_chain(
    const float* __restrict__ Wq, const float* __restrict__ Wk,
    const float* __restrict__ Wv, const float* __restrict__ G,
    float* __restrict__ Tm) {
  __shared__ __align__(16) float WqL[HH * ST];
  __shared__ __align__(16) float WkL[HH * ST];
  __shared__ __align__(16) float GL[TILE];
  __shared__ __align__(16) float WvT[TILE];
  __shared__ __align__(16) float Mr[8 * ST];
  __shared__ __align__(16) float Rr[8 * ST];

  const int t = (int)threadIdx.x;
  const int tx = t & 31, ty = t >> 5;
  const int blk = (int)blockIdx.x;
  const int b = blk / 9, rg = blk - b * 9;
  const int i = 8 * rg + ty;
  const bool alive = (i < DD);
  const int ic = alive ? i : 0;

  {
    float tq[17], tk[17];
#pragma unroll
    for (int q = 0; q < 17; q++) {
      const int idx = t + 256 * q;
      if (idx < HH * DD) { tq[q] = Wq[idx]; tk[q] = Wk[idx]; }
    }
#pragma unroll
    for (int q = 0; q < 17; q++) {
      const int idx = t + 256 * q;
      if (idx < HH * DD) {
        const int r = idx / DD, cc = idx - r * DD;
        WqL[r * ST + cc] = tq[q];
        WkL[r * ST + cc] = tk[q];
      }
    }
  }
  {
    const float4* Gb4 = (const float4*)(G + (size_t)b * TILE);
    float4 tG[5];
#pragma unroll
    for (int q = 0; q < 5; q++) {
      const int i4 = t + 256 * q;
      if (i4 < TILE / 4) tG[q] = Gb4[i4];
    }
#pragma unroll
    for (int q = 0; q < 5; q++) {
      const int i4 = t + 256 * q;
      if (i4 < TILE / 4) *((float4*)GL + i4) = tG[q];
    }
  }
  {
    float tv[17];
#pragma unroll
    for (int q = 0; q < 17; q++) {
      const int idx = t + 256 * q;
      if (idx < DD * DD) tv[q] = Wv[idx];
    }
#pragma unroll
    for (int q = 0; q < 17; q++) {
      const int idx = t + 256 * q;
      if (idx < DD * DD) {
        const int j = idx / DD, k = idx - j * DD;
        WvT[k * ST + j] = tv[q];
      }
    }
  }
  __syncthreads();

  {
    float m0 = 0.f, m1 = 0.f, m2 = 0.f;
    for (int h = 0; h < HH; h++) {
      const float wq = WqL[h * ST + ic];
      m0 = fmaf(wq, WkL[h * ST + tx], m0);
      m1 = fmaf(wq, WkL[h * ST + tx + 32], m1);
      m2 = fmaf(wq, WkL[h * ST + 64], m2);
    }
    if (alive) {
      Mr[ty * ST + tx] = m0;
      Mr[ty * ST + tx + 32] = m1;
      if (tx == 0) Mr[ty * ST + 64] = m2;
    }
  }
  __syncthreads();

  {
    float r0 = 0.f, r1 = 0.f, r2 = 0.f;
    for (int k = 0; k < DD; k++) {
      const float mm = Mr[ty * ST + k];
      r0 = fmaf(mm, GL[k * ST + tx], r0);
      r1 = fmaf(mm, GL[k * ST + tx + 32], r1);
      r2 = fmaf(mm, GL[k * ST + 64], r2);
    }
    if (alive) {
      Rr[ty * ST + tx] = r0;
      Rr[ty * ST + tx + 32] = r1;
      if (tx == 0) Rr[ty * ST + 64] = r2;
    }
  }
  __syncthreads();

  {
    float t0 = 0.f, t1 = 0.f, t2 = 0.f;
    for (int k = 0; k < DD; k++) {
      const float rv = Rr[ty * ST + k];
      t0 = fmaf(rv, WvT[k * ST + tx], t0);
      t1 = fmaf(rv, WvT[k * ST + tx + 32], t1);
      t2 = fmaf(rv, WvT[k * ST + 64], t2);
    }
    if (alive) {
      float* Tb = Tm + (size_t)b * TILE + (size_t)i * ST;
      Tb[tx] = t0;
      Tb[tx + 32] = t1;
      if (tx == 0) Tb[64] = t2;
    }
  }
}

// ---------------------------------------------------------------------------
// k3: out[b] = x[b] @ T[b]. 1024 blocks, __launch_bounds__(256,4) pins
// VGPR <= 128 -> 4 blocks/CU (vs 2 at VGPR=148). Tl staged async via
// global_load_lds (contiguous, zero staging regs); Xl reg-staged in 2x9
// passes. Edge col-64 computed unpredicated. Epilogue repacks the 4x4 reg
// tiles through LDS (reusing Xl) so global stores are coalesced float4.
// ---------------------------------------------------------------------------
__global__ __launch_bounds__(256, 4) void k3_out(const float* __restrict__ x,
                                                 const float* __restrict__ Tt,
                                                 float* __restrict__ out) {
  __shared__ __align__(16) float Tl[TILE];       // 17680 B
  __shared__ __align__(16) float Xl[64 * ST];    // 17408 B (reused as Ol)
  const int t = (int)threadIdx.x;
  const int tx = t & 15, ty = t >> 4;
  const int wid = t >> 6, lane = t & 63;
  const int blk = (int)blockIdx.x;
  const int b = blk >> 5;           // 32 blocks per batch
  const int rb = (blk & 31) * 64;
  const float4* Tg4 = (const float4*)(Tt + (size_t)b * TILE);
  const float* src = x + ((size_t)b * NN + rb) * DD;

  // ---- async stage T -> Tl: 1105 float4 slots, 16B/lane, fire-and-forget
#pragma unroll
  for (int q = 0; q < 4; q++) {
    const int s = q * 256 + wid * 64 + lane;          // < 1024
    GL2LDS(Tg4 + s, Tl + (size_t)(q * 256 + wid * 64) * 4);
  }
  {
    const int s = 1024 + wid * 64 + lane;             // tail: 81 slots
    if (s < TILE / 4) GL2LDS(Tg4 + s, Tl + (size_t)(1024 + wid * 64) * 4);
  }

  // ---- reg-stage x chunk -> Xl (padded), 2 passes x 9 temps
#pragma unroll
  for (int p = 0; p < 2; p++) {
    float tmp[9];
    const int cnt = (p == 1) ? 8 : 9;
#pragma unroll
    for (int q = 0; q < 9; q++) {
      const int idx = t + 256 * (9 * p + q);
      if (q < cnt && idx < 64 * DD) tmp[q] = src[idx];
    }
#pragma unroll
    for (int q = 0; q < 9; q++) {
      const int idx = t + 256 * (9 * p + q);
      if (q < cnt && idx < 64 * DD) {
        const int r = idx / DD;
        Xl[r * ST + (idx - r * DD)] = tmp[q];
      }
    }
  }
  __syncthreads();  // drains vmcnt -> Tl ready too

  float o[4][4] = {}, o64[4] = {};
  for (int kk = 0; kk < 64; kk += 4) {
    float xa4[4][4];  // [r][e]
    float tb4[4][4];  // [e][cc]
    float t64e[4];
#pragma unroll
    for (int r = 0; r < 4; r++)
      *(float4*)xa4[r] = *(const float4*)&Xl[(4 * ty + r) * ST + kk];
#pragma unroll
    for (int e = 0; e < 4; e++)
      *(float4*)tb4[e] = *(const float4*)&Tl[(kk + e) * ST + 4 * tx];
#pragma unroll
    for (int e = 0; e < 4; e++) t64e[e] = Tl[(kk + e) * ST + 64];
#pragma unroll
    for (int e = 0; e < 4; e++) {
#pragma unroll
      for (int r = 0; r < 4; r++)
#pragma unroll
        for (int cc = 0; cc < 4; cc++)
          o[r][cc] = fmaf(xa4[r][e], tb4[e][cc], o[r][cc]);
#pragma unroll
      for (int r = 0; r < 4; r++)
        o64[r] = fmaf(xa4[r][e], t64e[e], o64[r]);
    }
  }
  {  // k = 64 tail (unpredicated compute)
    float xs[4];
#pragma unroll
    for (int r = 0; r < 4; r++) xs[r] = Xl[(4 * ty + r) * ST + 64];
    float tb[4];
    *(float4*)tb = *(const float4*)&Tl[64 * ST + 4 * tx];
    const float t64 = Tl[64 * ST + 64];
#pragma unroll
    for (int r = 0; r < 4; r++) {
#pragma unroll
      for (int cc = 0; cc < 4; cc++)
        o[r][cc] = fmaf(xs[r], tb[cc], o[r][cc]);
      o64[r] = fmaf(xs[r], t64, o64[r]);
    }
  }

  // ---- epilogue: repack through LDS (reuse Xl) for coalesced f4 stores
  __syncthreads();  // everyone done reading Xl/Tl
  float* Ol = Xl;   // unpadded [64][65]
#pragma unroll
  for (int r = 0; r < 4; r++) {
#pragma unroll
    for (int cc = 0; cc < 4; cc++)
      Ol[(4 * ty + r) * DD + 4 * tx + cc] = o[r][cc];
  }
  if (tx == 0) {
#pragma unroll
    for (int r = 0; r < 4; r++) Ol[(4 * ty + r) * DD + 64] = o64[r];
  }
  __syncthreads();
  {
    float4* ob4 = (float4*)(out + ((size_t)b * NN + rb) * DD);  // 16B aligned
    const float4* Ol4 = (const float4*)Ol;
#pragma unroll
    for (int q = 0; q < 5; q++) {
      const int i4 = t + 256 * q;
      if (i4 < (64 * DD) / 4) ob4[i4] = Ol4[i4];
    }
  }
}

extern "C" void kernel_launch(void* const* d_in, const int* in_sizes, int n_in,
                              void* d_out, int out_size, void* d_ws,
                              size_t ws_size, hipStream_t stream) {
  const float* x = (const float*)d_in[0];
  const float* Wq = (const float*)d_in[1];
  const float* Wk = (const float*)d_in[2];
  const float* Wv = (const float*)d_in[3];
  float* out = (float*)d_out;

  float* P = (float*)d_ws;
  float* G = P + (size_t)BB * CC * TILE;
  float* Tm = G + (size_t)BB * TILE;

  k1_gram<<<BB * CC, 256, 0, stream>>>(x, P);
  kred<<<BB * 5, 256, 0, stream>>>(P, G);
  k2_chain<<<BB * 9, 256, 0, stream>>>(Wq, Wk, Wv, G, Tm);
  k3_out<<<BB * CC, 256, 0, stream>>>(x, Tm, out);
  (void)in_sizes; (void)n_in; (void)out_size; (void)ws_size;
}